// Round 1
// baseline (849.143 us; speedup 1.0000x reference)
//
#include <hip/hip_runtime.h>
#include <hip/hip_bf16.h>
#include <math.h>

// Problem constants
#define NN   2048
#define EE   32768
#define NS   32
#define NV   16
#define NB   8          // NUM_BASIS
#define DD   32
#define TT   32
#define LL   2
#define HRD  64
#define NWW  3072
#define PI_F 3.14159265358979323846f

// scales
#define SC_SCS (1.0f/32.0f)                 // 1/sqrt(NS*D)
#define SC_SCV 0.04419417382415922f         // 1/sqrt(NV*D)=1/sqrt(512)
#define SC_L1S 0.17677669529663687f         // 1/sqrt(32)
#define SC_L1V 0.25f                        // 1/sqrt(16)
#define SC_R1  0.25f                        // 1/sqrt(2B)
#define SC_R2  0.125f                       // 1/sqrt(HR)
#define SC_ES  0.10206207261596575f         // 1/sqrt(96)
#define SC_EV  0.125f                       // 1/sqrt(64)
#define SC_AGG 0.25f                        // 1/sqrt(16)
#define SC_L2S 0.14433756729740643f         // 1/sqrt(48)
#define SC_L2V 0.25f
#define SC_SIS 0.17677669529663687f
#define SC_SIV 0.25f

// ---------------------------------------------------------------- K0: QR
// LAPACK-convention Householder QR of W_uplift (16x2) -> Q (16x2)
__global__ void k_qr(const float* __restrict__ Wup, float* __restrict__ Q) {
    if (threadIdx.x != 0 || blockIdx.x != 0) return;
    double A[16][2], tau[2];
    for (int i = 0; i < 16; ++i)
        for (int j = 0; j < 2; ++j) A[i][j] = (double)Wup[i*2 + j];
    for (int j = 0; j < 2; ++j) {
        double alpha = A[j][j];
        double xn2 = 0.0;
        for (int i = j + 1; i < 16; ++i) xn2 += A[i][j]*A[i][j];
        if (xn2 == 0.0) {
            tau[j] = 0.0;
        } else {
            double nrm  = sqrt(alpha*alpha + xn2);
            double beta = (alpha >= 0.0) ? -nrm : nrm;
            tau[j] = (beta - alpha) / beta;
            double s = 1.0 / (alpha - beta);
            for (int i = j + 1; i < 16; ++i) A[i][j] *= s;
            A[j][j] = beta;
        }
        for (int k = j + 1; k < 2; ++k) {
            double w = A[j][k];
            for (int i = j + 1; i < 16; ++i) w += A[i][j]*A[i][k];
            w *= tau[j];
            A[j][k] -= w;
            for (int i = j + 1; i < 16; ++i) A[i][k] -= A[i][j]*w;
        }
    }
    double Qm[16][2];
    for (int i = 0; i < 16; ++i)
        for (int j = 0; j < 2; ++j) Qm[i][j] = (i == j) ? 1.0 : 0.0;
    for (int j = 1; j >= 0; --j) {
        for (int k = 0; k < 2; ++k) {
            double w = Qm[j][k];
            for (int i = j + 1; i < 16; ++i) w += A[i][j]*Qm[i][k];
            w *= tau[j];
            Qm[j][k] -= w;
            for (int i = j + 1; i < 16; ++i) Qm[i][k] -= A[i][j]*w;
        }
    }
    for (int i = 0; i < 16; ++i)
        for (int j = 0; j < 2; ++j) Q[i*2 + j] = (float)Qm[i][j];
}

// ------------------------------------------------- K1: per-type sc weights
// WtS[l][t][i][j] = sum_a emb[t,a]*W_sc_s[l,i,a,j]   (i<32, j<48)
// WtV[l][t][c][j] = sum_a emb[t,a]*W_sc_v[l,c,a,j]   (c<16, j<16)
__global__ void k_typew(const float* __restrict__ emb,
                        const float* __restrict__ Wscs,
                        const float* __restrict__ Wscv,
                        float* __restrict__ WtS, float* __restrict__ WtV) {
    int lt = blockIdx.x;
    int l = lt >> 5, t = lt & 31;
    __shared__ float es[32];
    if (threadIdx.x < 32) es[threadIdx.x] = emb[t*DD + threadIdx.x];
    __syncthreads();
    const float* Ws = Wscs + (size_t)l*NS*DD*48;
    float* oS = WtS + (size_t)(l*TT + t)*NS*48;
    for (int idx = threadIdx.x; idx < NS*48; idx += 256) {
        int i = idx / 48, j = idx % 48;
        float acc = 0.f;
        for (int a = 0; a < 32; ++a) acc += es[a]*Ws[(i*DD + a)*48 + j];
        oS[idx] = acc;
    }
    const float* Wv = Wscv + (size_t)l*NV*DD*NV;
    float* oV = WtV + (size_t)(l*TT + t)*NV*NV;
    for (int idx = threadIdx.x; idx < NV*NV; idx += 256) {
        int c = idx / 16, j = idx % 16;
        float acc = 0.f;
        for (int a = 0; a < 32; ++a) acc += es[a]*Wv[(c*DD + a)*NV + j];
        oV[idx] = acc;
    }
}

// ------------------------------------------------------------- K2: init y
__global__ void k_init(const float* __restrict__ xin, const float* __restrict__ Q,
                       float* __restrict__ ys0, float* __restrict__ yv0,
                       float* __restrict__ ys1, float* __restrict__ yv1,
                       float* __restrict__ xcur) {
    int n = blockIdx.x*256 + threadIdx.x;  // exactly 2048
    float xl[6];
    for (int i = 0; i < 6; ++i) { xl[i] = xin[n*6 + i]; xcur[n*6 + i] = xl[i]; }
    for (int j = 0; j < 32; ++j) { ys0[n*32 + j] = 0.f; ys1[n*32 + j] = 0.f; }
    for (int c = 0; c < 16; ++c)
        for (int k = 0; k < 3; ++k) {
            float v = Q[c*2 + 0]*xl[k] + Q[c*2 + 1]*xl[3 + k];
            yv0[n*48 + c*3 + k] = v;
            yv1[n*48 + c*3 + k] = v;
        }
}

// -------------------------------------------- K3: edge geometry + radial1
__global__ void k_edge(const float* __restrict__ xcur,
                       const int* __restrict__ esrc, const int* __restrict__ edst,
                       const float* __restrict__ Wr1l,
                       float* __restrict__ hrg, float* __restrict__ eag) {
    __shared__ float Wr1[16*64];
    for (int i = threadIdx.x; i < 16*64; i += 256) Wr1[i] = Wr1l[i];
    __syncthreads();
    int e = blockIdx.x*256 + threadIdx.x;  // exactly 32768
    int s = esrc[e], d = edst[e];
    float ef[16];
    for (int m = 0; m < 2; ++m) {
        float v0 = xcur[s*6 + m*3 + 0] - xcur[d*6 + m*3 + 0];
        float v1 = xcur[s*6 + m*3 + 1] - xcur[d*6 + m*3 + 1];
        float v2 = xcur[s*6 + m*3 + 2] - xcur[d*6 + m*3 + 2];
        float len = sqrtf(v0*v0 + v1*v1 + v2*v2 + 1e-12f);
        float inv = 1.0f/len;
        // bessel basis via sin recurrence: sin((b+1)*theta)
        float theta = len*(PI_F/3.0f);
        float s1v = sinf(theta), c1v = cosf(theta);
        float sc  = 2.3094010767585034f*inv;  // sqrt(2/3)*sqrt(8)
        float sp = 0.f, scur = s1v, twoc = 2.f*c1v;
        for (int b = 0; b < 8; ++b) {
            ef[m*8 + b] = sc*scur;
            float sn = twoc*scur - sp;
            sp = scur; scur = sn;
        }
        // smooth cutoff * sqrt(3)*vec/len
        float u = 2.0f*(len*(1.0f/3.0f) - 1.0f);
        float cut;
        if (u > 0.f) cut = 0.f;
        else if (u < -1.f) cut = 1.f;
        else cut = 0.5f*(1.0f - cosf(PI_F*u));
        float shs = 1.7320508075688772f*inv*cut;
        eag[e*6 + m*3 + 0] = shs*v0;
        eag[e*6 + m*3 + 1] = shs*v1;
        eag[e*6 + m*3 + 2] = shs*v2;
    }
    // hr = silu(ef @ W_r1 * SC_R1)
    for (int hh = 0; hh < 64; ++hh) {
        float z = 0.f;
        for (int f = 0; f < 16; ++f) z += ef[f]*Wr1[f*64 + hh];
        z *= SC_R1;
        hrg[e*64 + hh] = z/(1.0f + expf(-z));
    }
}

// ---------------------------------------- K4: node lin1 + zero aggregators
__global__ void k_nodepre(const float* __restrict__ ys, const float* __restrict__ yv,
                          const float* __restrict__ Wl1s, const float* __restrict__ Wl1v,
                          float* __restrict__ s1, float* __restrict__ v1,
                          float* __restrict__ nsb, float* __restrict__ nvb) {
    int idx = blockIdx.x*256 + threadIdx.x;  // exactly 2048*48
    int n = idx / 48, r = idx % 48;
    nsb[idx] = 0.f;
    nvb[idx] = 0.f;
    if (r < 32) {
        float acc = 0.f;
        for (int i = 0; i < 32; ++i) acc += ys[n*32 + i]*Wl1s[i*32 + r];
        s1[n*32 + r] = acc*SC_L1S;
    }
    int j = r/3, k = r - 3*j;
    float acc = 0.f;
    for (int c = 0; c < 16; ++c) acc += yv[n*48 + c*3 + k]*Wl1v[c*16 + j];
    v1[idx] = acc*SC_L1V;
}

// ------------------------------ K5: fused radial2-GEMM + edge TP + scatter
// block: 256 threads, 64 edges. thread (te,tc): edges 4te..4te+3; owns cols
// with col%16 == tc; private register accumulators; flush = global atomics.
__global__ void __launch_bounds__(256) k_tp(
        const float* __restrict__ hrg, const float* __restrict__ eag,
        const float* __restrict__ s1g, const float* __restrict__ v1g,
        const int* __restrict__ esrc, const int* __restrict__ edst,
        const float* __restrict__ Wr2l,
        float* __restrict__ nsb, float* __restrict__ nvb) {
    __shared__ __align__(16) float hr_s[64][68];   // pad 68: avoids b128 4-way bank alias
    __shared__ float Wc[64][64];                   // Wc[h][c]
    __shared__ float s1_s[64][32];
    __shared__ float v1_s[64][48];
    __shared__ float dots_s[64][32];               // [e][c*2+m]
    __shared__ float ea_s[64][6];
    __shared__ int   src_s[64];

    int tid = threadIdx.x;
    int te = tid >> 4, tc = tid & 15;
    int ebase = blockIdx.x*64;

    if (tid < 64) src_s[tid] = esrc[ebase + tid];
    __syncthreads();
    for (int i = tid; i < 64*64; i += 256) hr_s[i >> 6][i & 63] = hrg[(size_t)ebase*64 + i];
    for (int i = tid; i < 64*6; i += 256)  ea_s[i/6][i%6] = eag[(size_t)ebase*6 + i];
    for (int i = tid; i < 64*32; i += 256) {
        int e = i >> 5, s = i & 31;
        s1_s[e][s] = s1g[src_s[e]*32 + s];
    }
    for (int i = tid; i < 64*48; i += 256) {
        int e = i/48, j = i%48;
        v1_s[e][j] = v1g[src_s[e]*48 + j];
    }
    __syncthreads();
    for (int i = tid; i < 64*32; i += 256) {
        int e = i >> 5, cm = i & 31, c = cm >> 1, m = cm & 1;
        dots_s[e][cm] = v1_s[e][c*3+0]*ea_s[e][m*3+0]
                      + v1_s[e][c*3+1]*ea_s[e][m*3+1]
                      + v1_s[e][c*3+2]*ea_s[e][m*3+2];
    }

    float accES[4][3] = {{0,0,0},{0,0,0},{0,0,0},{0,0,0}};
    float accEV[4][3] = {{0,0,0},{0,0,0},{0,0,0},{0,0,0}};
    int e0 = 4*te;

    const float4* h0 = (const float4*)(&hr_s[e0 + 0][0]);
    const float4* h1 = (const float4*)(&hr_s[e0 + 1][0]);
    const float4* h2 = (const float4*)(&hr_s[e0 + 2][0]);
    const float4* h3 = (const float4*)(&hr_s[e0 + 3][0]);

    for (int ch = 0; ch < 48; ++ch) {
        __syncthreads();  // protect previous chunk's Wc reads (and initial dots)
        for (int i = tid; i < 64*64; i += 256)
            Wc[i >> 6][i & 63] = Wr2l[(size_t)(i >> 6)*NWW + ch*64 + (i & 63)];
        __syncthreads();

        // w[q][i] = sum_h hr[e0+i][h] * W_r2[h][ch*64 + q*16 + tc]
        float w[4][4] = {{0,0,0,0},{0,0,0,0},{0,0,0,0},{0,0,0,0}};
        for (int hq = 0; hq < 16; ++hq) {
            float4 a0 = h0[hq], a1 = h1[hq], a2 = h2[hq], a3 = h3[hq];
            #pragma unroll
            for (int dq = 0; dq < 4; ++dq) {
                int hh = hq*4 + dq;
                float b0 = Wc[hh][tc], b1 = Wc[hh][tc + 16];
                float b2 = Wc[hh][tc + 32], b3 = Wc[hh][tc + 48];
                float av0 = (&a0.x)[dq], av1 = (&a1.x)[dq];
                float av2 = (&a2.x)[dq], av3 = (&a3.x)[dq];
                w[0][0] += b0*av0; w[0][1] += b0*av1; w[0][2] += b0*av2; w[0][3] += b0*av3;
                w[1][0] += b1*av0; w[1][1] += b1*av1; w[1][2] += b1*av2; w[1][3] += b1*av3;
                w[2][0] += b2*av0; w[2][1] += b2*av1; w[2][2] += b2*av2; w[2][3] += b2*av3;
                w[3][0] += b3*av0; w[3][1] += b3*av1; w[3][2] += b3*av2; w[3][3] += b3*av3;
            }
        }

        if (ch < 16) {              // sv region: col = s*32 + m*16 + j, j = tc
            #pragma unroll
            for (int q = 0; q < 4; ++q) {
                int col = ch*64 + q*16 + tc;
                int sidx = col >> 5, m = (col >> 4) & 1;
                #pragma unroll
                for (int i = 0; i < 4; ++i) {
                    float f = w[q][i]*s1_s[e0 + i][sidx];
                    accEV[i][0] += f*ea_s[e0 + i][m*3 + 0];
                    accEV[i][1] += f*ea_s[e0 + i][m*3 + 1];
                    accEV[i][2] += f*ea_s[e0 + i][m*3 + 2];
                }
            }
        } else if (ch < 40) {       // vs region: col1 = c*96 + m*48 + j48
            #pragma unroll
            for (int q = 0; q < 4; ++q) {
                int col1 = ch*64 - 1024 + q*16 + tc;
                int c = col1/96;
                int rem = col1 - c*96;
                int m = rem/48;
                int j48 = rem - m*48;
                int g = j48 >> 4;   // j48 % 16 == tc
                #pragma unroll
                for (int i = 0; i < 4; ++i)
                    accES[i][g] += w[q][i]*dots_s[e0 + i][c*2 + m];
            }
        } else {                    // vv region: col2 = c*32 + m*16 + j, j = tc
            #pragma unroll
            for (int q = 0; q < 4; ++q) {
                int col2 = ch*64 - 2560 + q*16 + tc;
                int c = col2 >> 5, m = (col2 >> 4) & 1;
                #pragma unroll
                for (int i = 0; i < 4; ++i) {
                    float ww = w[q][i];
                    const float* v  = &v1_s[e0 + i][c*3];
                    const float* aa = &ea_s[e0 + i][m*3];
                    accEV[i][0] += ww*(v[1]*aa[2] - v[2]*aa[1]);
                    accEV[i][1] += ww*(v[2]*aa[0] - v[0]*aa[2]);
                    accEV[i][2] += ww*(v[0]*aa[1] - v[1]*aa[0]);
                }
            }
        }
    }

    const float sES = SC_R2*SC_ES*SC_AGG;
    const float sEV = SC_R2*SC_EV*SC_AGG;
    for (int i = 0; i < 4; ++i) {
        int d = edst[ebase + e0 + i];
        atomicAdd(&nsb[d*48 +  0 + tc], accES[i][0]*sES);
        atomicAdd(&nsb[d*48 + 16 + tc], accES[i][1]*sES);
        atomicAdd(&nsb[d*48 + 32 + tc], accES[i][2]*sES);
        atomicAdd(&nvb[d*48 + tc*3 + 0], accEV[i][0]*sEV);
        atomicAdd(&nvb[d*48 + tc*3 + 1], accEV[i][1]*sEV);
        atomicAdd(&nvb[d*48 + tc*3 + 2], accEV[i][2]*sEV);
    }
}

// ----------------------- K6: node update (conv, gate, si, leapfrog, project)
// block 256 = 4 waves, one wave per node
__global__ void __launch_bounds__(256) k_nodepost(
        const float* __restrict__ ysC, const float* __restrict__ yvC,
        float* __restrict__ ysO, float* __restrict__ yvO,
        const float* __restrict__ nsb, const float* __restrict__ nvb,
        const int* __restrict__ nattr,
        const float* __restrict__ WtSl, const float* __restrict__ WtVl,
        const float* __restrict__ Wl2s, const float* __restrict__ Wl2v,
        const float* __restrict__ Wsis, const float* __restrict__ Wsiv,
        const float* __restrict__ harr, const float* __restrict__ mixarr, int l,
        float* __restrict__ xcur, float* __restrict__ xout2,
        const float* __restrict__ Qg) {
    int wave = threadIdx.x >> 6, lane = threadIdx.x & 63;
    int n = blockIdx.x*4 + wave;
    __shared__ float ys_s[4][32], yv_s[4][48], ns_s[4][48], nv_s[4][48];
    __shared__ float cs_s[4][48], nvo_s[4][48];

    if (lane < 32) ys_s[wave][lane] = ysC[n*32 + lane];
    if (lane < 48) {
        yv_s[wave][lane] = yvC[n*48 + lane];
        ns_s[wave][lane] = nsb[n*48 + lane];
        nv_s[wave][lane] = nvb[n*48 + lane];
    }
    __syncthreads();
    int t = nattr[n];
    const float* WtSn = WtSl + (size_t)t*NS*48;
    const float* WtVn = WtVl + (size_t)t*NV*NV;
    float hv = harr[l];
    float h2 = hv*hv, mx = mixarr[l];

    if (lane < 48) {
        float sc = 0.f, s2 = 0.f;
        for (int i = 0; i < 32; ++i) sc += ys_s[wave][i]*WtSn[i*48 + lane];
        for (int c = 0; c < 48; ++c) s2 += ns_s[wave][c]*Wl2s[c*48 + lane];
        cs_s[wave][lane] = sc*SC_SCS + s2*SC_L2S;
    }
    __syncthreads();
    if (lane < 48) {
        int j = lane/3, k = lane - 3*j;
        float scv = 0.f, v2 = 0.f, siv = 0.f;
        for (int c = 0; c < 16; ++c) {
            float yvv = yv_s[wave][c*3 + k];
            scv += yvv*WtVn[c*16 + j];
            v2  += nv_s[wave][c*3 + k]*Wl2v[c*16 + j];
            siv += yvv*Wsiv[c*16 + j];
        }
        float convv = scv*SC_SCV + v2*SC_L2V;
        siv *= SC_SIV;
        float gate = 1.f/(1.f + expf(-cs_s[wave][32 + j]));
        float gv = gate*convv;
        float nvnew = 2.f*yv_s[wave][lane] - yvO[n*48 + lane] + h2*(mx*gv + (mx - 1.f)*siv);
        nvo_s[wave][lane] = nvnew;
        yvO[n*48 + lane] = nvnew;
    }
    if (lane < 32) {
        float sis = 0.f;
        for (int i = 0; i < 32; ++i) sis += ys_s[wave][i]*Wsis[i*32 + lane];
        sis *= SC_SIS;
        float cs = cs_s[wave][lane];
        float gs = cs/(1.f + expf(-cs));
        float nsnew = 2.f*ys_s[wave][lane] - ysO[n*32 + lane] + h2*(mx*gs + (mx - 1.f)*sis);
        ysO[n*32 + lane] = nsnew;
    }
    __syncthreads();
    if (lane < 6) {
        int i = lane/3, k = lane - 3*(lane/3);
        float acc = 0.f;
        for (int c = 0; c < 16; ++c) acc += Qg[c*2 + i]*nvo_s[wave][c*3 + k];
        xcur[n*6 + lane]  = acc;
        xout2[n*6 + lane] = acc;
    }
}

// ---------------------------------------------------------------- launch
extern "C" void kernel_launch(void* const* d_in, const int* in_sizes, int n_in,
                              void* d_out, int out_size, void* d_ws, size_t ws_size,
                              hipStream_t stream) {
    const float* x_in  = (const float*)d_in[0];
    const int*   nattr = (const int*)  d_in[2];
    const int*   esrc  = (const int*)  d_in[3];
    const int*   edst  = (const int*)  d_in[4];
    const float* emb   = (const float*)d_in[5];
    const float* Wup   = (const float*)d_in[6];
    const float* Wscs  = (const float*)d_in[7];
    const float* Wscv  = (const float*)d_in[8];
    const float* Wl1s  = (const float*)d_in[9];
    const float* Wl1v  = (const float*)d_in[10];
    const float* Wr1   = (const float*)d_in[11];
    const float* Wr2   = (const float*)d_in[12];
    const float* Wl2s  = (const float*)d_in[13];
    const float* Wl2v  = (const float*)d_in[14];
    const float* Wsis  = (const float*)d_in[15];
    const float* Wsiv  = (const float*)d_in[16];
    const float* harr  = (const float*)d_in[17];
    const float* mixar = (const float*)d_in[18];
    float* out = (float*)d_out;

    float* ws = (float*)d_ws;
    size_t off = 0;
    float* Q    = ws + off; off += 32;
    float* WtS  = ws + off; off += (size_t)LL*TT*NS*48;     // 98304
    float* WtV  = ws + off; off += (size_t)LL*TT*NV*NV;     // 16384
    float* ys0  = ws + off; off += (size_t)NN*32;
    float* yv0  = ws + off; off += (size_t)NN*48;
    float* ys1  = ws + off; off += (size_t)NN*32;
    float* yv1  = ws + off; off += (size_t)NN*48;
    float* xcur = ws + off; off += (size_t)NN*6;
    float* s1   = ws + off; off += (size_t)NN*32;
    float* v1   = ws + off; off += (size_t)NN*48;
    float* nsb  = ws + off; off += (size_t)NN*48;
    float* nvb  = ws + off; off += (size_t)NN*48;
    float* eab  = ws + off; off += (size_t)EE*6;
    float* hrb  = ws + off; off += (size_t)EE*64;

    k_qr<<<1, 1, 0, stream>>>(Wup, Q);
    k_typew<<<LL*TT, 256, 0, stream>>>(emb, Wscs, Wscv, WtS, WtV);
    k_init<<<NN/256, 256, 0, stream>>>(x_in, Q, ys0, yv0, ys1, yv1, xcur);

    float* curS = ys0; float* curV = yv0;
    float* oldS = ys1; float* oldV = yv1;
    for (int l = 0; l < LL; ++l) {
        k_edge<<<EE/256, 256, 0, stream>>>(xcur, esrc, edst, Wr1 + (size_t)l*16*64, hrb, eab);
        k_nodepre<<<NN*48/256, 256, 0, stream>>>(curS, curV, Wl1s + (size_t)l*32*32,
                                                 Wl1v + (size_t)l*16*16, s1, v1, nsb, nvb);
        k_tp<<<EE/64, 256, 0, stream>>>(hrb, eab, s1, v1, esrc, edst,
                                        Wr2 + (size_t)l*HRD*NWW, nsb, nvb);
        float* xo2 = (l == LL - 1) ? out : xcur;
        k_nodepost<<<NN/4, 256, 0, stream>>>(curS, curV, oldS, oldV, nsb, nvb, nattr,
                                             WtS + (size_t)l*TT*NS*48, WtV + (size_t)l*TT*NV*NV,
                                             Wl2s + (size_t)l*48*48, Wl2v + (size_t)l*16*16,
                                             Wsis + (size_t)l*32*32, Wsiv + (size_t)l*16*16,
                                             harr, mixar, l, xcur, xo2, Q);
        float* ts = curS; curS = oldS; oldS = ts;
        float* tv = curV; curV = oldV; oldV = tv;
    }
}

// Round 2
// 412.016 us; speedup vs baseline: 2.0609x; 2.0609x over previous
//
#include <hip/hip_runtime.h>
#include <hip/hip_bf16.h>
#include <math.h>

// Problem constants
#define NN   2048
#define EE   32768
#define NS   32
#define NV   16
#define NB   8          // NUM_BASIS
#define DD   32
#define TT   32
#define LL   2
#define HRD  64
#define NWW  3072
#define PI_F 3.14159265358979323846f

// scales
#define SC_SCS (1.0f/32.0f)                 // 1/sqrt(NS*D)
#define SC_SCV 0.04419417382415922f         // 1/sqrt(NV*D)=1/sqrt(512)
#define SC_L1S 0.17677669529663687f         // 1/sqrt(32)
#define SC_L1V 0.25f                        // 1/sqrt(16)
#define SC_R1  0.25f                        // 1/sqrt(2B)
#define SC_R2  0.125f                       // 1/sqrt(HR)
#define SC_ES  0.10206207261596575f         // 1/sqrt(96)
#define SC_EV  0.125f                       // 1/sqrt(64)
#define SC_AGG 0.25f                        // 1/sqrt(16)
#define SC_L2S 0.14433756729740643f         // 1/sqrt(48)
#define SC_L2V 0.25f
#define SC_SIS 0.17677669529663687f
#define SC_SIV 0.25f

typedef __attribute__((ext_vector_type(8))) short  short8;   // 8 bf16 (4 VGPRs)
typedef __attribute__((ext_vector_type(4))) float  floatx4;  // MFMA C/D

// ---------------------------------------------------------------- K0: QR
// LAPACK-convention Householder QR of W_uplift (16x2) -> Q (16x2)
__global__ void k_qr(const float* __restrict__ Wup, float* __restrict__ Q) {
    if (threadIdx.x != 0 || blockIdx.x != 0) return;
    double A[16][2], tau[2];
    for (int i = 0; i < 16; ++i)
        for (int j = 0; j < 2; ++j) A[i][j] = (double)Wup[i*2 + j];
    for (int j = 0; j < 2; ++j) {
        double alpha = A[j][j];
        double xn2 = 0.0;
        for (int i = j + 1; i < 16; ++i) xn2 += A[i][j]*A[i][j];
        if (xn2 == 0.0) {
            tau[j] = 0.0;
        } else {
            double nrm  = sqrt(alpha*alpha + xn2);
            double beta = (alpha >= 0.0) ? -nrm : nrm;
            tau[j] = (beta - alpha) / beta;
            double s = 1.0 / (alpha - beta);
            for (int i = j + 1; i < 16; ++i) A[i][j] *= s;
            A[j][j] = beta;
        }
        for (int k = j + 1; k < 2; ++k) {
            double w = A[j][k];
            for (int i = j + 1; i < 16; ++i) w += A[i][j]*A[i][k];
            w *= tau[j];
            A[j][k] -= w;
            for (int i = j + 1; i < 16; ++i) A[i][k] -= A[i][j]*w;
        }
    }
    double Qm[16][2];
    for (int i = 0; i < 16; ++i)
        for (int j = 0; j < 2; ++j) Qm[i][j] = (i == j) ? 1.0 : 0.0;
    for (int j = 1; j >= 0; --j) {
        for (int k = 0; k < 2; ++k) {
            double w = Qm[j][k];
            for (int i = j + 1; i < 16; ++i) w += A[i][j]*Qm[i][k];
            w *= tau[j];
            Qm[j][k] -= w;
            for (int i = j + 1; i < 16; ++i) Qm[i][k] -= A[i][j]*w;
        }
    }
    for (int i = 0; i < 16; ++i)
        for (int j = 0; j < 2; ++j) Q[i*2 + j] = (float)Qm[i][j];
}

// ------------------------------------------------- K1: per-type sc weights
__global__ void k_typew(const float* __restrict__ emb,
                        const float* __restrict__ Wscs,
                        const float* __restrict__ Wscv,
                        float* __restrict__ WtS, float* __restrict__ WtV) {
    int lt = blockIdx.x;
    int l = lt >> 5, t = lt & 31;
    __shared__ float es[32];
    if (threadIdx.x < 32) es[threadIdx.x] = emb[t*DD + threadIdx.x];
    __syncthreads();
    const float* Ws = Wscs + (size_t)l*NS*DD*48;
    float* oS = WtS + (size_t)(l*TT + t)*NS*48;
    for (int idx = threadIdx.x; idx < NS*48; idx += 256) {
        int i = idx / 48, j = idx % 48;
        float acc = 0.f;
        for (int a = 0; a < 32; ++a) acc += es[a]*Ws[(i*DD + a)*48 + j];
        oS[idx] = acc;
    }
    const float* Wv = Wscv + (size_t)l*NV*DD*NV;
    float* oV = WtV + (size_t)(l*TT + t)*NV*NV;
    for (int idx = threadIdx.x; idx < NV*NV; idx += 256) {
        int c = idx / 16, j = idx % 16;
        float acc = 0.f;
        for (int a = 0; a < 32; ++a) acc += es[a]*Wv[(c*DD + a)*NV + j];
        oV[idx] = acc;
    }
}

// --------------------------------------- K1b: W_r2 -> bf16, transposed [col][k]
__global__ void k_convw(const float* __restrict__ Wr2, __hip_bfloat16* __restrict__ wr2t) {
    int idx = blockIdx.x*256 + threadIdx.x;    // L*64*3072 total, reads coalesced
    int l = idx / (HRD*NWW);
    int r = idx - l*(HRD*NWW);
    int k = r / NWW;
    int c = r - k*NWW;
    wr2t[((size_t)l*NWW + c)*HRD + k] = __float2bfloat16(Wr2[idx]);
}

// ------------------------------------------------------------- K2: init y
__global__ void k_init(const float* __restrict__ xin, const float* __restrict__ Q,
                       float* __restrict__ ys0, float* __restrict__ yv0,
                       float* __restrict__ ys1, float* __restrict__ yv1,
                       float* __restrict__ xcur) {
    int n = blockIdx.x*256 + threadIdx.x;  // exactly 2048
    float xl[6];
    for (int i = 0; i < 6; ++i) { xl[i] = xin[n*6 + i]; xcur[n*6 + i] = xl[i]; }
    for (int j = 0; j < 32; ++j) { ys0[n*32 + j] = 0.f; ys1[n*32 + j] = 0.f; }
    for (int c = 0; c < 16; ++c)
        for (int k = 0; k < 3; ++k) {
            float v = Q[c*2 + 0]*xl[k] + Q[c*2 + 1]*xl[3 + k];
            yv0[n*48 + c*3 + k] = v;
            yv1[n*48 + c*3 + k] = v;
        }
}

// -------------------------------------------- K3: edge geometry + radial1
__global__ void k_edge(const float* __restrict__ xcur,
                       const int* __restrict__ esrc, const int* __restrict__ edst,
                       const float* __restrict__ Wr1l,
                       __hip_bfloat16* __restrict__ hrg, float* __restrict__ eag) {
    __shared__ float Wr1[16*64];
    for (int i = threadIdx.x; i < 16*64; i += 256) Wr1[i] = Wr1l[i];
    __syncthreads();
    int e = blockIdx.x*256 + threadIdx.x;  // exactly 32768
    int s = esrc[e], d = edst[e];
    float ef[16];
    for (int m = 0; m < 2; ++m) {
        float v0 = xcur[s*6 + m*3 + 0] - xcur[d*6 + m*3 + 0];
        float v1 = xcur[s*6 + m*3 + 1] - xcur[d*6 + m*3 + 1];
        float v2 = xcur[s*6 + m*3 + 2] - xcur[d*6 + m*3 + 2];
        float len = sqrtf(v0*v0 + v1*v1 + v2*v2 + 1e-12f);
        float inv = 1.0f/len;
        // bessel basis via sin recurrence: sin((b+1)*theta)
        float theta = len*(PI_F/3.0f);
        float s1v = sinf(theta), c1v = cosf(theta);
        float sc  = 2.3094010767585034f*inv;  // sqrt(2/3)*sqrt(8)
        float sp = 0.f, scur = s1v, twoc = 2.f*c1v;
        for (int b = 0; b < 8; ++b) {
            ef[m*8 + b] = sc*scur;
            float sn = twoc*scur - sp;
            sp = scur; scur = sn;
        }
        // smooth cutoff * sqrt(3)*vec/len
        float u = 2.0f*(len*(1.0f/3.0f) - 1.0f);
        float cut;
        if (u > 0.f) cut = 0.f;
        else if (u < -1.f) cut = 1.f;
        else cut = 0.5f*(1.0f - cosf(PI_F*u));
        float shs = 1.7320508075688772f*inv*cut;
        eag[e*6 + m*3 + 0] = shs*v0;
        eag[e*6 + m*3 + 1] = shs*v1;
        eag[e*6 + m*3 + 2] = shs*v2;
    }
    // hr = silu(ef @ W_r1 * SC_R1), store bf16
    for (int hh = 0; hh < 64; ++hh) {
        float z = 0.f;
        for (int f = 0; f < 16; ++f) z += ef[f]*Wr1[f*64 + hh];
        z *= SC_R1;
        hrg[(size_t)e*64 + hh] = __float2bfloat16(z/(1.0f + expf(-z)));
    }
}

// ---------------------------------------- K4: node lin1 + zero aggregators
__global__ void k_nodepre(const float* __restrict__ ys, const float* __restrict__ yv,
                          const float* __restrict__ Wl1s, const float* __restrict__ Wl1v,
                          float* __restrict__ s1, float* __restrict__ v1,
                          float* __restrict__ nsb, float* __restrict__ nvb) {
    int idx = blockIdx.x*256 + threadIdx.x;  // exactly 2048*48
    int n = idx / 48, r = idx % 48;
    nsb[idx] = 0.f;
    nvb[idx] = 0.f;
    if (r < 32) {
        float acc = 0.f;
        for (int i = 0; i < 32; ++i) acc += ys[n*32 + i]*Wl1s[i*32 + r];
        s1[n*32 + r] = acc*SC_L1S;
    }
    int j = r/3, k = r - 3*j;
    float acc = 0.f;
    for (int c = 0; c < 16; ++c) acc += yv[n*48 + c*3 + k]*Wl1v[c*16 + j];
    v1[idx] = acc*SC_L1V;
}

// ------------------------------ K5: fused radial2-MFMA + edge TP + scatter
// block: 256 threads = 4 waves, 64 edges. Wave w computes edge-tile w*16 via
// mfma_f32_16x16x32_bf16; C layout (col=lane&15, row=(lane>>4)*4+reg) makes
// lane own cols q*16+tc (tc=tid&15) for edges 4*(tid>>4)+i — same mapping as
// the scalar version, so the TP epilogue/atomics are unchanged.
__global__ void __launch_bounds__(256) k_tp(
        const __hip_bfloat16* __restrict__ hrg, const float* __restrict__ eag,
        const float* __restrict__ s1g, const float* __restrict__ v1g,
        const int* __restrict__ esrc, const int* __restrict__ edst,
        const __hip_bfloat16* __restrict__ wr2tl,
        float* __restrict__ nsb, float* __restrict__ nvb) {
    __shared__ float s1_s[64][33];     // odd strides: quads hit distinct banks
    __shared__ float v1_s[64][49];
    __shared__ float dots_s[64][33];   // [e][c*2+m]
    __shared__ float ea_s[64][9];
    __shared__ int   src_s[64];

    int tid = threadIdx.x;
    int wave = tid >> 6, lane = tid & 63;
    int te = tid >> 4, tc = tid & 15;
    int quad = lane >> 4;
    int ebase = blockIdx.x*64;

    if (tid < 64) src_s[tid] = esrc[ebase + tid];
    __syncthreads();
    for (int i = tid; i < 64*6; i += 256)  ea_s[i/6][i%6] = eag[(size_t)ebase*6 + i];
    for (int i = tid; i < 64*32; i += 256) {
        int e = i >> 5, s = i & 31;
        s1_s[e][s] = s1g[src_s[e]*32 + s];
    }
    for (int i = tid; i < 64*48; i += 256) {
        int e = i/48, j = i%48;
        v1_s[e][j] = v1g[src_s[e]*48 + j];
    }
    __syncthreads();
    for (int i = tid; i < 64*32; i += 256) {
        int e = i >> 5, cm = i & 31, c = cm >> 1, m = cm & 1;
        dots_s[e][cm] = v1_s[e][c*3+0]*ea_s[e][m*3+0]
                      + v1_s[e][c*3+1]*ea_s[e][m*3+1]
                      + v1_s[e][c*3+2]*ea_s[e][m*3+2];
    }
    __syncthreads();

    // A fragments (chunk-invariant): lane holds hr[arow][quad*8 + j], j=0..7
    const short* hr16 = (const short*)hrg;
    const short* w16  = (const short*)wr2tl;
    int arow = ebase + wave*16 + (lane & 15);
    short8 a_lo = *(const short8*)(hr16 + (size_t)arow*64 + quad*8);
    short8 a_hi = *(const short8*)(hr16 + (size_t)arow*64 + 32 + quad*8);

    float accES[4][3] = {{0,0,0},{0,0,0},{0,0,0},{0,0,0}};
    float accEV[4][3] = {{0,0,0},{0,0,0},{0,0,0},{0,0,0}};
    int e0 = 4*te;   // == wave*16 + quad*4

    for (int ch = 0; ch < 48; ++ch) {
        // w[q] = C-frag: w[q][i] = sum_k hr[e0+i][k] * W_r2[k][ch*64+q*16+tc]
        floatx4 w4[4];
        #pragma unroll
        for (int q = 0; q < 4; ++q) {
            int col = ch*64 + q*16 + tc;
            const short* bp = w16 + (size_t)col*64 + quad*8;
            short8 b_lo = *(const short8*)(bp);
            short8 b_hi = *(const short8*)(bp + 32);
            floatx4 c = {0.f, 0.f, 0.f, 0.f};
            c = __builtin_amdgcn_mfma_f32_16x16x32_bf16(a_lo, b_lo, c, 0, 0, 0);
            c = __builtin_amdgcn_mfma_f32_16x16x32_bf16(a_hi, b_hi, c, 0, 0, 0);
            w4[q] = c;
        }

        if (ch < 16) {              // sv region: col = s*32 + m*16 + j, j = tc
            #pragma unroll
            for (int q = 0; q < 4; ++q) {
                int col = ch*64 + q*16 + tc;
                int sidx = col >> 5, m = (col >> 4) & 1;
                #pragma unroll
                for (int i = 0; i < 4; ++i) {
                    float f = w4[q][i]*s1_s[e0 + i][sidx];
                    accEV[i][0] += f*ea_s[e0 + i][m*3 + 0];
                    accEV[i][1] += f*ea_s[e0 + i][m*3 + 1];
                    accEV[i][2] += f*ea_s[e0 + i][m*3 + 2];
                }
            }
        } else if (ch < 40) {       // vs region: col1 = c*96 + m*48 + j48
            #pragma unroll
            for (int q = 0; q < 4; ++q) {
                int col1 = ch*64 - 1024 + q*16 + tc;
                int c = col1/96;
                int rem = col1 - c*96;
                int m = rem/48;
                int j48 = rem - m*48;
                int g = j48 >> 4;   // j48 % 16 == tc
                #pragma unroll
                for (int i = 0; i < 4; ++i)
                    accES[i][g] += w4[q][i]*dots_s[e0 + i][c*2 + m];
            }
        } else {                    // vv region: col2 = c*32 + m*16 + j, j = tc
            #pragma unroll
            for (int q = 0; q < 4; ++q) {
                int col2 = ch*64 - 2560 + q*16 + tc;
                int c = col2 >> 5, m = (col2 >> 4) & 1;
                #pragma unroll
                for (int i = 0; i < 4; ++i) {
                    float ww = w4[q][i];
                    const float* v  = &v1_s[e0 + i][c*3];
                    const float* aa = &ea_s[e0 + i][m*3];
                    accEV[i][0] += ww*(v[1]*aa[2] - v[2]*aa[1]);
                    accEV[i][1] += ww*(v[2]*aa[0] - v[0]*aa[2]);
                    accEV[i][2] += ww*(v[0]*aa[1] - v[1]*aa[0]);
                }
            }
        }
    }

    const float sES = SC_R2*SC_ES*SC_AGG;
    const float sEV = SC_R2*SC_EV*SC_AGG;
    for (int i = 0; i < 4; ++i) {
        int d = edst[ebase + e0 + i];
        atomicAdd(&nsb[d*48 +  0 + tc], accES[i][0]*sES);
        atomicAdd(&nsb[d*48 + 16 + tc], accES[i][1]*sES);
        atomicAdd(&nsb[d*48 + 32 + tc], accES[i][2]*sES);
        atomicAdd(&nvb[d*48 + tc*3 + 0], accEV[i][0]*sEV);
        atomicAdd(&nvb[d*48 + tc*3 + 1], accEV[i][1]*sEV);
        atomicAdd(&nvb[d*48 + tc*3 + 2], accEV[i][2]*sEV);
    }
}

// ----------------------- K6: node update (conv, gate, si, leapfrog, project)
__global__ void __launch_bounds__(256) k_nodepost(
        const float* __restrict__ ysC, const float* __restrict__ yvC,
        float* __restrict__ ysO, float* __restrict__ yvO,
        const float* __restrict__ nsb, const float* __restrict__ nvb,
        const int* __restrict__ nattr,
        const float* __restrict__ WtSl, const float* __restrict__ WtVl,
        const float* __restrict__ Wl2s, const float* __restrict__ Wl2v,
        const float* __restrict__ Wsis, const float* __restrict__ Wsiv,
        const float* __restrict__ harr, const float* __restrict__ mixarr, int l,
        float* __restrict__ xcur, float* __restrict__ xout2,
        const float* __restrict__ Qg) {
    int wave = threadIdx.x >> 6, lane = threadIdx.x & 63;
    int n = blockIdx.x*4 + wave;
    __shared__ float ys_s[4][32], yv_s[4][48], ns_s[4][48], nv_s[4][48];
    __shared__ float cs_s[4][48], nvo_s[4][48];

    if (lane < 32) ys_s[wave][lane] = ysC[n*32 + lane];
    if (lane < 48) {
        yv_s[wave][lane] = yvC[n*48 + lane];
        ns_s[wave][lane] = nsb[n*48 + lane];
        nv_s[wave][lane] = nvb[n*48 + lane];
    }
    __syncthreads();
    int t = nattr[n];
    const float* WtSn = WtSl + (size_t)t*NS*48;
    const float* WtVn = WtVl + (size_t)t*NV*NV;
    float hv = harr[l];
    float h2 = hv*hv, mx = mixarr[l];

    if (lane < 48) {
        float sc = 0.f, s2 = 0.f;
        for (int i = 0; i < 32; ++i) sc += ys_s[wave][i]*WtSn[i*48 + lane];
        for (int c = 0; c < 48; ++c) s2 += ns_s[wave][c]*Wl2s[c*48 + lane];
        cs_s[wave][lane] = sc*SC_SCS + s2*SC_L2S;
    }
    __syncthreads();
    if (lane < 48) {
        int j = lane/3, k = lane - 3*j;
        float scv = 0.f, v2 = 0.f, siv = 0.f;
        for (int c = 0; c < 16; ++c) {
            float yvv = yv_s[wave][c*3 + k];
            scv += yvv*WtVn[c*16 + j];
            v2  += nv_s[wave][c*3 + k]*Wl2v[c*16 + j];
            siv += yvv*Wsiv[c*16 + j];
        }
        float convv = scv*SC_SCV + v2*SC_L2V;
        siv *= SC_SIV;
        float gate = 1.f/(1.f + expf(-cs_s[wave][32 + j]));
        float gv = gate*convv;
        float nvnew = 2.f*yv_s[wave][lane] - yvO[n*48 + lane] + h2*(mx*gv + (mx - 1.f)*siv);
        nvo_s[wave][lane] = nvnew;
        yvO[n*48 + lane] = nvnew;
    }
    if (lane < 32) {
        float sis = 0.f;
        for (int i = 0; i < 32; ++i) sis += ys_s[wave][i]*Wsis[i*32 + lane];
        sis *= SC_SIS;
        float cs = cs_s[wave][lane];
        float gs = cs/(1.f + expf(-cs));
        float nsnew = 2.f*ys_s[wave][lane] - ysO[n*32 + lane] + h2*(mx*gs + (mx - 1.f)*sis);
        ysO[n*32 + lane] = nsnew;
    }
    __syncthreads();
    if (lane < 6) {
        int i = lane/3, k = lane - 3*(lane/3);
        float acc = 0.f;
        for (int c = 0; c < 16; ++c) acc += Qg[c*2 + i]*nvo_s[wave][c*3 + k];
        xcur[n*6 + lane]  = acc;
        xout2[n*6 + lane] = acc;
    }
}

// ---------------------------------------------------------------- launch
extern "C" void kernel_launch(void* const* d_in, const int* in_sizes, int n_in,
                              void* d_out, int out_size, void* d_ws, size_t ws_size,
                              hipStream_t stream) {
    const float* x_in  = (const float*)d_in[0];
    const int*   nattr = (const int*)  d_in[2];
    const int*   esrc  = (const int*)  d_in[3];
    const int*   edst  = (const int*)  d_in[4];
    const float* emb   = (const float*)d_in[5];
    const float* Wup   = (const float*)d_in[6];
    const float* Wscs  = (const float*)d_in[7];
    const float* Wscv  = (const float*)d_in[8];
    const float* Wl1s  = (const float*)d_in[9];
    const float* Wl1v  = (const float*)d_in[10];
    const float* Wr1   = (const float*)d_in[11];
    const float* Wr2   = (const float*)d_in[12];
    const float* Wl2s  = (const float*)d_in[13];
    const float* Wl2v  = (const float*)d_in[14];
    const float* Wsis  = (const float*)d_in[15];
    const float* Wsiv  = (const float*)d_in[16];
    const float* harr  = (const float*)d_in[17];
    const float* mixar = (const float*)d_in[18];
    float* out = (float*)d_out;

    float* ws = (float*)d_ws;
    size_t off = 0;
    float* Q    = ws + off; off += 32;
    float* WtS  = ws + off; off += (size_t)LL*TT*NS*48;     // 98304
    float* WtV  = ws + off; off += (size_t)LL*TT*NV*NV;     // 16384
    float* ys0  = ws + off; off += (size_t)NN*32;
    float* yv0  = ws + off; off += (size_t)NN*48;
    float* ys1  = ws + off; off += (size_t)NN*32;
    float* yv1  = ws + off; off += (size_t)NN*48;
    float* xcur = ws + off; off += (size_t)NN*6;
    float* s1   = ws + off; off += (size_t)NN*32;
    float* v1   = ws + off; off += (size_t)NN*48;
    float* nsb  = ws + off; off += (size_t)NN*48;
    float* nvb  = ws + off; off += (size_t)NN*48;
    float* eab  = ws + off; off += (size_t)EE*6;
    off = (off + 3) & ~(size_t)3;                           // 16B align
    __hip_bfloat16* hrb  = (__hip_bfloat16*)(ws + off); off += (size_t)EE*64/2;       // bf16
    __hip_bfloat16* wr2t = (__hip_bfloat16*)(ws + off); off += (size_t)LL*NWW*HRD/2;  // bf16

    k_qr<<<1, 1, 0, stream>>>(Wup, Q);
    k_typew<<<LL*TT, 256, 0, stream>>>(emb, Wscs, Wscv, WtS, WtV);
    k_convw<<<LL*HRD*NWW/256, 256, 0, stream>>>(Wr2, wr2t);
    k_init<<<NN/256, 256, 0, stream>>>(x_in, Q, ys0, yv0, ys1, yv1, xcur);

    float* curS = ys0; float* curV = yv0;
    float* oldS = ys1; float* oldV = yv1;
    for (int l = 0; l < LL; ++l) {
        k_edge<<<EE/256, 256, 0, stream>>>(xcur, esrc, edst, Wr1 + (size_t)l*16*64, hrb, eab);
        k_nodepre<<<NN*48/256, 256, 0, stream>>>(curS, curV, Wl1s + (size_t)l*32*32,
                                                 Wl1v + (size_t)l*16*16, s1, v1, nsb, nvb);
        k_tp<<<EE/64, 256, 0, stream>>>(hrb, eab, s1, v1, esrc, edst,
                                        wr2t + (size_t)l*NWW*HRD, nsb, nvb);
        float* xo2 = (l == LL - 1) ? out : xcur;
        k_nodepost<<<NN/4, 256, 0, stream>>>(curS, curV, oldS, oldV, nsb, nvb, nattr,
                                             WtS + (size_t)l*TT*NS*48, WtV + (size_t)l*TT*NV*NV,
                                             Wl2s + (size_t)l*48*48, Wl2v + (size_t)l*16*16,
                                             Wsis + (size_t)l*32*32, Wsiv + (size_t)l*16*16,
                                             harr, mixar, l, xcur, xo2, Q);
        float* ts = curS; curS = oldS; oldS = ts;
        float* tv = curV; curV = oldV; oldV = tv;
    }
}